// Round 4
// baseline (669.036 us; speedup 1.0000x reference)
//
#include <hip/hip_runtime.h>
#include <stdint.h>

#define B_ 256
#define T_ 128
#define I_ 2048
#define H_ 128
#define G_ 512   // 4*H
#define O_ 2

typedef _Float16 half8 __attribute__((ext_vector_type(8)));
typedef float f32x4 __attribute__((ext_vector_type(4)));

// async global->LDS, 16B per lane, wave-uniform LDS base + lane*16
__device__ __forceinline__ void gll16(const void* g, void* l) {
    __builtin_amdgcn_global_load_lds((const __attribute__((address_space(1))) unsigned int*)g,
                                     (__attribute__((address_space(3))) unsigned int*)l,
                                     16, 0, 0);
}

// ---------------- Wi[k][n] -> Wt[n][k] fp16, tiled transpose ----------------
__global__ void wt2(const float* __restrict__ Wi, _Float16* __restrict__ Wt) {
    __shared__ float tile[32][33];
    const int k0 = (blockIdx.x >> 4) * 32;   // 64 k-tiles
    const int n0 = (blockIdx.x & 15) * 32;   // 16 n-tiles
    const int t = threadIdx.x;
    const int r = t >> 5, c = t & 31;
    #pragma unroll
    for (int i = 0; i < 4; ++i)
        tile[r + 8 * i][c] = Wi[(size_t)(k0 + r + 8 * i) * G_ + n0 + c];
    __syncthreads();
    #pragma unroll
    for (int i = 0; i < 4; ++i)
        Wt[(size_t)(n0 + r + 8 * i) * I_ + k0 + c] = (_Float16)tile[c][r + 8 * i];
}

// ---------------- xg = x @ Wi  (m97 structure: gll staging, dbuf, swizzled LDS) ----
// A fp32 [128][32] per buf (16KB), B fp16 [128][32] (8KB); cvt A->fp16 at frag load.
// A swizzle: 16B-unit u of row r stored at pos u ^ (r&7)   (8 units/row)
// B swizzle: 16B-unit u of row r stored at pos u ^ fB(r), fB(r)=((r&3)+((r>>2)&3))&3
__launch_bounds__(256, 3)
__global__ void gemm_xg(const float* __restrict__ X, const _Float16* __restrict__ Wt,
                        _Float16* __restrict__ xg) {
    __shared__ float    lds_a[2][128 * 32];   // 2 x 16KB
    __shared__ _Float16 lds_b[2][128 * 32];   // 2 x 8KB

    // XCD swizzle: 1024 blocks (%8==0 -> bijective); 4 col-tiles of a row-panel
    // land on the same XCD for A-panel L2 reuse.
    const int bid = blockIdx.x;
    const int swz = (bid & 7) * 128 + (bid >> 3);
    const int m0 = (swz >> 2) * 128;
    const int n0 = (swz & 3) * 128;

    const int tid = threadIdx.x;
    const int l = tid & 63, w = tid >> 6;
    const int wm = w >> 1, wn = w & 1;      // 2x2 waves, 64x64 out each
    const int lr = l & 15;
    const int q  = l >> 4;                  // k-quad 0..3 (k = q*8..q*8+7)

    // --- staging source addresses (pre-swizzled per rule #21) ---
    // A: wave w stages chunks 4w..4w+3; chunk = 8 rows x 32 f32 (1KB)
    const int a_unit = (l & 7) ^ (l >> 3);                  // src unit for linear pos l&7
    const float* aglb = X + (size_t)(m0 + w * 32 + (l >> 3)) * I_ + a_unit * 4;
    // B: wave w stages chunks 2w, 2w+1; chunk = 16 rows x 32 f16 (1KB)
    const int b_r4 = (l >> 2) & 3;          // r&3 at store
    const int b_r2 = (l >> 4) & 3;          // (r>>2)&3 at store
    const int b_unit = (l & 3) ^ ((b_r4 + b_r2) & 3);
    const _Float16* bglb = Wt + (size_t)(n0 + w * 32 + (l >> 2)) * I_ + b_unit * 8;

    f32x4 acc[4][4];
    #pragma unroll
    for (int mi = 0; mi < 4; ++mi)
        #pragma unroll
        for (int ni = 0; ni < 4; ++ni)
            acc[mi][ni] = (f32x4){0.f, 0.f, 0.f, 0.f};

    // prologue: stage kt=0 into buf 0
    #pragma unroll
    for (int cc = 0; cc < 4; ++cc)
        gll16(aglb + (size_t)cc * 8 * I_, (char*)&lds_a[0][0] + (w * 4 + cc) * 1024);
    #pragma unroll
    for (int cc = 0; cc < 2; ++cc)
        gll16(bglb + (size_t)cc * 16 * I_, (char*)&lds_b[0][0] + (w * 2 + cc) * 1024);
    __syncthreads();   // drains vmcnt -> buf0 ready

    for (int kt = 0; kt < I_ / 32; ++kt) {
        const int cur = kt & 1;
        if (kt < I_ / 32 - 1) {   // stage next tile into buf cur^1
            const int ko = (kt + 1) * 32;
            #pragma unroll
            for (int cc = 0; cc < 4; ++cc)
                gll16(aglb + ko + (size_t)cc * 8 * I_,
                      (char*)&lds_a[cur ^ 1][0] + (w * 4 + cc) * 1024);
            #pragma unroll
            for (int cc = 0; cc < 2; ++cc)
                gll16(bglb + ko + (size_t)cc * 16 * I_,
                      (char*)&lds_b[cur ^ 1][0] + (w * 2 + cc) * 1024);
        }

        // fragments from buf cur (swizzled reads, <=2-way conflicts)
        half8 af[4], bf[4];
        #pragma unroll
        for (int mi = 0; mi < 4; ++mi) {
            const int row = wm * 64 + mi * 16 + lr;
            const int plo = (2 * q) ^ (row & 7);
            const int phi = plo ^ 1;
            f32x4 lo = *(const f32x4*)&lds_a[cur][row * 32 + plo * 4];
            f32x4 hi = *(const f32x4*)&lds_a[cur][row * 32 + phi * 4];
            half8 h;
            h[0]=(_Float16)lo[0]; h[1]=(_Float16)lo[1]; h[2]=(_Float16)lo[2]; h[3]=(_Float16)lo[3];
            h[4]=(_Float16)hi[0]; h[5]=(_Float16)hi[1]; h[6]=(_Float16)hi[2]; h[7]=(_Float16)hi[3];
            af[mi] = h;
        }
        #pragma unroll
        for (int ni = 0; ni < 4; ++ni) {
            const int row = wn * 64 + ni * 16 + lr;
            const int fB = ((row & 3) + ((row >> 2) & 3)) & 3;
            bf[ni] = *(const half8*)&lds_b[cur][row * 32 + (q ^ fB) * 8];
        }
        #pragma unroll
        for (int mi = 0; mi < 4; ++mi)
            #pragma unroll
            for (int ni = 0; ni < 4; ++ni)
                acc[mi][ni] = __builtin_amdgcn_mfma_f32_16x16x32_f16(af[mi], bf[ni], acc[mi][ni], 0, 0, 0);

        __syncthreads();   // drains vm+lgkm; next buf published, cur reusable
    }

    // epilogue: C col = lane&15, row = (lane>>4)*4 + r (m89-verified); store fp16
    #pragma unroll
    for (int mi = 0; mi < 4; ++mi) {
        #pragma unroll
        for (int ni = 0; ni < 4; ++ni) {
            const int col = n0 + wn * 64 + ni * 16 + lr;
            #pragma unroll
            for (int r = 0; r < 4; ++r) {
                const int row = m0 + wm * 64 + mi * 16 + q * 4 + r;
                xg[(size_t)row * G_ + col] = (_Float16)acc[mi][ni][r];
            }
        }
    }
}

// ---------------- LSTM scan: 4-way k-split, dbuf h, shuffle reduce ----------------
__device__ __forceinline__ float sigmoidf_fast(float x) {
    return 1.f / (1.f + __expf(-x));
}
__device__ __forceinline__ float tanhf_fast(float x) {
    return 1.f - 2.f / (__expf(2.f * x) + 1.f);
}

__launch_bounds__(512, 2)
__global__ void lstm_scan(const _Float16* __restrict__ xg, const float* __restrict__ Uh,
                          const float* __restrict__ bias, const float* __restrict__ Wout,
                          const float* __restrict__ bout, float* __restrict__ out) {
    // h copies: h4[buf][p][36] ; slice p holds h[32p..32p+32); pad 36 staggers banks
    __shared__ float h4[2][4][36];
    const int t = threadIdx.x;
    const int w = t >> 6, l = t & 63;
    const int lr = l & 15, p = l >> 4;       // p = k-slice 0..3
    const int j = w * 16 + lr;               // hidden unit 0..127

    // U[m][c] = Uh[(32p+m)][j+128c] : 128 VGPRs
    float U[32][4];
    #pragma unroll
    for (int m = 0; m < 32; ++m)
        #pragma unroll
        for (int c = 0; c < 4; ++c)
            U[m][c] = Uh[(size_t)(32 * p + m) * G_ + j + 128 * c];
    float bj[4];
    #pragma unroll
    for (int c = 0; c < 4; ++c) bj[c] = bias[j + 128 * c];

    for (int idx = t; idx < 2 * 4 * 36; idx += 512) ((float*)h4)[idx] = 0.f;

    const _Float16* xgb = xg + (size_t)blockIdx.x * T_ * G_;
    float xv[4], xn[4] = {0.f, 0.f, 0.f, 0.f};
    #pragma unroll
    for (int c = 0; c < 4; ++c) xv[c] = (float)xgb[j + 128 * c];
    float cst = 0.f;
    const int wslice = w >> 1;               // this wave's h-slice ownership
    const float seed = (p == 0) ? 1.f : 0.f; // BUGFIX r3: xv+bj must enter the
                                             // cross-slice reduction exactly ONCE
    __syncthreads();

    for (int tt = 0; tt < T_; ++tt) {
        const int rb = tt & 1;
        if (tt < T_ - 1) {                   // T14: prefetch next timestep's xg
            #pragma unroll
            for (int c = 0; c < 4; ++c) xn[c] = (float)xgb[(size_t)(tt + 1) * G_ + j + 128 * c];
        }
        float z0 = seed * (xv[0] + bj[0]), z1 = seed * (xv[1] + bj[1]);
        float z2 = seed * (xv[2] + bj[2]), z3 = seed * (xv[3] + bj[3]);
        #pragma unroll
        for (int i = 0; i < 8; ++i) {
            f32x4 hv = *(const f32x4*)&h4[rb][p][i * 4];   // bank-staggered, conflict-free
            #pragma unroll
            for (int mm = 0; mm < 4; ++mm) {
                const float hk = hv[mm];
                z0 += hk * U[i * 4 + mm][0];
                z1 += hk * U[i * 4 + mm][1];
                z2 += hk * U[i * 4 + mm][2];
                z3 += hk * U[i * 4 + mm][3];
            }
        }
        // reduce partials across the 4 k-slices (lanes 16, then 32 apart)
        z0 += __shfl_xor(z0, 16); z0 += __shfl_xor(z0, 32);
        z1 += __shfl_xor(z1, 16); z1 += __shfl_xor(z1, 32);
        z2 += __shfl_xor(z2, 16); z2 += __shfl_xor(z2, 32);
        z3 += __shfl_xor(z3, 16); z3 += __shfl_xor(z3, 32);
        // gates (flax order i,f,g,o); identical on all 4 p-lanes (commutative adds)
        const float si = sigmoidf_fast(z0);
        const float sf = sigmoidf_fast(z1);
        const float tg = tanhf_fast(z2);
        const float so = sigmoidf_fast(z3);
        cst = sf * cst + si * tg;
        const float hn = so * tanhf_fast(cst);
        if (p == wslice) h4[rb ^ 1][p][j & 31] = hn;   // 16 lanes/wave, consecutive banks
        #pragma unroll
        for (int c = 0; c < 4; ++c) xv[c] = xn[c];
        __syncthreads();                      // publish new h buf
    }

    if (t < O_) {  // out[b] = h_f @ Wout + bout ; final h is in buf 0 (T_ even)
        float a0 = 0.f, a1 = 0.f, a2 = 0.f, a3 = 0.f;
        for (int k = 0; k < H_; k += 4) {
            a0 += h4[0][(k + 0) >> 5][(k + 0) & 31] * Wout[(k + 0) * O_ + t];
            a1 += h4[0][(k + 1) >> 5][(k + 1) & 31] * Wout[(k + 1) * O_ + t];
            a2 += h4[0][(k + 2) >> 5][(k + 2) & 31] * Wout[(k + 2) * O_ + t];
            a3 += h4[0][(k + 3) >> 5][(k + 3) & 31] * Wout[(k + 3) * O_ + t];
        }
        out[blockIdx.x * O_ + t] = a0 + a1 + a2 + a3 + bout[t];
    }
}

extern "C" void kernel_launch(void* const* d_in, const int* in_sizes, int n_in,
                              void* d_out, int out_size, void* d_ws, size_t ws_size,
                              hipStream_t stream) {
    const float* x    = (const float*)d_in[0];
    const float* Wi   = (const float*)d_in[1];
    const float* Uh   = (const float*)d_in[2];
    const float* bias = (const float*)d_in[3];
    const float* Wout = (const float*)d_in[4];
    const float* bout = (const float*)d_in[5];
    float* out = (float*)d_out;

    _Float16* Wt = (_Float16*)d_ws;                                            // 2 MB
    _Float16* xg = (_Float16*)((char*)d_ws + (size_t)G_ * I_ * sizeof(_Float16)); // 32 MB

    wt2<<<1024, 256, 0, stream>>>(Wi, Wt);
    gemm_xg<<<(B_ * T_ / 128) * (G_ / 128), 256, 0, stream>>>(x, Wt, xg);
    lstm_scan<<<B_, 512, 0, stream>>>(xg, Uh, bias, Wout, bout, out);
}